// Round 20
// baseline (418.000 us; speedup 1.0000x reference)
//
#include <hip/hip_runtime.h>
#include <hip/hip_bf16.h>
#include <stdint.h>

#define BB 4
#define NN 2048
#define CC 1024
#define HH 16
#define DD 64

typedef __attribute__((ext_vector_type(8))) short bf16x8;
typedef __attribute__((ext_vector_type(4))) float f32x4;

#define LOG2E 1.44269504088896f

// raw v_exp_f32: D = 2^S0 (verified r12: matches exp2f numerics, absmax unchanged)
__device__ __forceinline__ float exp2_hw(float x) {
  float r;
  asm("v_exp_f32 %0, %1" : "=v"(r) : "v"(x));
  return r;
}
#define EXP2(x) exp2_hw(x)

// ---------- small helpers ----------
__device__ __forceinline__ unsigned short f2bf(float x) {
  uint32_t u = __float_as_uint(x);
  uint32_t r = (u + 0x7FFFu + ((u >> 16) & 1u)) >> 16;   // RNE
  return (unsigned short)r;
}
__device__ __forceinline__ float bf2f(unsigned short v) {
  return __uint_as_float(((uint32_t)v) << 16);
}
__device__ __forceinline__ float load_in_f(const void* p, size_t idx, int f32in) {
  if (f32in) return ((const float*)p)[idx];
  return bf2f(((const uint16_t*)p)[idx]);
}
// async global->LDS, 16B per lane; lds ptr must be the wave-uniform base
__device__ __forceinline__ void gload16(uint16_t* lds_base, const uint16_t* gsrc) {
  __builtin_amdgcn_global_load_lds(
      (const __attribute__((address_space(1))) uint32_t*)(const void*)gsrc,
      (__attribute__((address_space(3))) uint32_t*)(void*)lds_base,
      16, 0, 0);
}

// ---------- dtype detection ----------
__global__ void detect_kernel(const uint32_t* __restrict__ q,
                              const uint32_t* __restrict__ m,
                              int* __restrict__ flags) {
  if (threadIdx.x == 0 && blockIdx.x == 0) {
    int sane = 0;
    for (int i = 0; i < 128; ++i) {
      uint32_t w = q[i];
      int e0 = (int)((w >> 7) & 0xFFu);
      int e1 = (int)((w >> 23) & 0xFFu);
      sane += (e0 >= 0x70 && e0 <= 0x8F) ? 1 : 0;
      sane += (e1 >= 0x70 && e1 <= 0x8F) ? 1 : 0;
    }
    flags[0] = (sane >= 208) ? 0 : 1;   // 1 => fp32 inputs
    int allsmall = 1;
    for (int i = 0; i < 16; ++i) if (m[i] > 1u) allsmall = 0;
    flags[1] = allsmall;                 // 1 => mask is int32
  }
}

// ---------- merged prep: z=0..2 qkv->bf16, z=3 mask bitpack, z=4 ratio ----------
__global__ void prep_kernel(const void* __restrict__ s0, const void* __restrict__ s1,
                            const void* __restrict__ s2, const void* __restrict__ ratio,
                            const void* __restrict__ mask,
                            uint16_t* __restrict__ d0, uint16_t* __restrict__ d1,
                            uint16_t* __restrict__ d2,
                            float* __restrict__ rs, float* __restrict__ ng,
                            uint32_t* __restrict__ mb, const int* __restrict__ flags) {
  const int z = blockIdx.z;
  if (z < 3) {
    const int f32in = flags[0];
    const void* src = (z == 0) ? s0 : (z == 1) ? s1 : s2;
    uint16_t* dst = (z == 0) ? d0 : (z == 1) ? d1 : d2;
    int idx = blockIdx.x * blockDim.x + threadIdx.x;
    const int total = (BB * NN * CC) >> 2;
    const int stride = gridDim.x * blockDim.x;
    if (f32in) {
      const float4* s = (const float4*)src;
      for (; idx < total; idx += stride) {
        float4 v = s[idx];
        ushort4 o;
        o.x = f2bf(v.x); o.y = f2bf(v.y); o.z = f2bf(v.z); o.w = f2bf(v.w);
        ((ushort4*)dst)[idx] = o;
      }
    } else {
      const ushort4* s = (const ushort4*)src;
      for (; idx < total; idx += stride) ((ushort4*)dst)[idx] = s[idx];
    }
  } else if (z == 3) {
    const int isint = flags[1];
    const int gw = (blockIdx.x * blockDim.x + threadIdx.x) >> 6;
    const int lane = threadIdx.x & 63;
    const int nw = (gridDim.x * blockDim.x) >> 6;
    const int totalw = (BB * NN * NN) >> 6;
    for (int w = gw; w < totalw; w += nw) {
      int e = w * 64 + lane;
      bool m;
      if (isint) m = (((const int*)mask)[e] != 0);
      else       m = (((const uint8_t*)mask)[e] != 0);
      unsigned long long bal = __ballot(m);
      if (lane == 0) ((unsigned long long*)mb)[w] = bal;
    }
  } else {
    const int f32in = flags[0];
    int idx = blockIdx.x * blockDim.x + threadIdx.x;
    if (idx < BB * NN) {
      float r = load_in_f(ratio, idx, f32in);
      rs[idx] = r * 0.125f * LOG2E;
      ng[idx] = r * (-1e9f) * LOG2E;
    }
  }
}

// ---------- W transpose + bf16 convert: Wt[n][k] = W[k][n] ----------
__global__ __launch_bounds__(256)
void transW(const void* w0, const void* w1, const void* w2, const void* w3,
            uint16_t* __restrict__ wt, const int* __restrict__ flags) {
  const int f32in = flags[0];
  const void* src = (blockIdx.z == 0) ? w0 : (blockIdx.z == 1) ? w1
                   : (blockIdx.z == 2) ? w2 : w3;
  uint16_t* dst = wt + (size_t)blockIdx.z * CC * CC;
  __shared__ float t[32][33];
  const int tx = threadIdx.x, ty = threadIdx.y;
  const int n0 = blockIdx.x * 32, k0 = blockIdx.y * 32;
#pragma unroll
  for (int r = 0; r < 4; ++r) {
    int k = k0 + ty + r * 8;
    t[ty + r * 8][tx] = load_in_f(src, (size_t)k * CC + n0 + tx, f32in);
  }
  __syncthreads();
#pragma unroll
  for (int r = 0; r < 4; ++r) {
    int n = n0 + ty + r * 8;
    dst[(size_t)n * CC + k0 + tx] = f2bf(t[tx][ty + r * 8]);
  }
}

// ---------- fused QKV projection: grid (64, 24); blockIdx.y selects q/k/v third ----------
__global__ __launch_bounds__(256, 2)
void gemmQKV(const uint16_t* __restrict__ xq, const uint16_t* __restrict__ xk,
             const uint16_t* __restrict__ xv, const uint16_t* __restrict__ Wt,
             uint16_t* __restrict__ qb, uint16_t* __restrict__ kb,
             uint16_t* __restrict__ vtb, const float* __restrict__ rowscale) {
  __shared__ uint16_t As[128 * 32];
  __shared__ uint16_t Bs[128 * 32];
  const int tid = threadIdx.x;
  const int wid = tid >> 6, lane = tid & 63;
  const int g = lane >> 4, c = lane & 15;
  const int n0g = blockIdx.y * 128;
  const int sel = n0g >> 10;
  const int n0 = n0g & 1023;
  const int m0 = blockIdx.x * 128;
  const uint16_t* A = (sel == 0) ? xq : (sel == 1) ? xk : xv;
  const uint16_t* Bt = Wt + (size_t)sel * CC * CC;
  const int wr = wid >> 1, wc = wid & 1;
  f32x4 acc[4][4] = {};
  for (int k0 = 0; k0 < 1024; k0 += 32) {
    __syncthreads();
#pragma unroll
    for (int is = 0; is < 2; ++is) {
      int sb = is * 256 + wid * 64;
      int s = sb + lane;
      int r = s >> 2, kp = s & 3;
      int kps = kp ^ ((r >> 1) & 3);
      gload16(&As[sb * 8], A + (size_t)(m0 + r) * 1024 + k0 + kps * 8);
      gload16(&Bs[sb * 8], Bt + (size_t)(n0 + r) * 1024 + k0 + kps * 8);
    }
    __syncthreads();
    bf16x8 a[4], b[4];
#pragma unroll
    for (int mi = 0; mi < 4; ++mi) {
      int row = wr * 64 + mi * 16 + c;
      a[mi] = *(const bf16x8*)&As[row * 32 + (g ^ ((row >> 1) & 3)) * 8];
    }
#pragma unroll
    for (int ni = 0; ni < 4; ++ni) {
      int row = wc * 64 + ni * 16 + c;
      b[ni] = *(const bf16x8*)&Bs[row * 32 + (g ^ ((row >> 1) & 3)) * 8];
    }
#pragma unroll
    for (int mi = 0; mi < 4; ++mi)
#pragma unroll
      for (int ni = 0; ni < 4; ++ni)
        acc[mi][ni] = __builtin_amdgcn_mfma_f32_16x16x32_bf16(a[mi], b[ni], acc[mi][ni], 0, 0, 0);
  }
  float rsv[4][4];
  if (sel == 1) {
#pragma unroll
    for (int mi = 0; mi < 4; ++mi)
#pragma unroll
      for (int r = 0; r < 4; ++r)
        rsv[mi][r] = rowscale[m0 + wr * 64 + mi * 16 + g * 4 + r];
  }
#pragma unroll
  for (int mi = 0; mi < 4; ++mi)
#pragma unroll
    for (int ni = 0; ni < 4; ++ni)
#pragma unroll
      for (int r = 0; r < 4; ++r) {
        int mrow = m0 + wr * 64 + mi * 16 + g * 4 + r;
        int ncol = n0 + wc * 64 + ni * 16 + c;
        float v = acc[mi][ni][r];
        int b_ = mrow >> 11, i = mrow & 2047, h = ncol >> 6, d = ncol & 63;
        if (sel == 0) {
          qb[((size_t)(b_ * 16 + h) * 2048 + i) * 64 + d] = f2bf(v);
        } else if (sel == 1) {
          kb[((size_t)(b_ * 16 + h) * 2048 + i) * 64 + d] = f2bf(v * rsv[mi][r]);
        } else {
          vtb[((size_t)(b_ * 16 + h) * 64 + d) * 2048 + i] = f2bf(v);
        }
      }
}

// ---------- output GEMM: out fp32 [M][C] = acc + resid ----------
__global__ __launch_bounds__(256, 2)
void gemmO(const uint16_t* __restrict__ A, const uint16_t* __restrict__ Bt,
           float* __restrict__ out, const void* __restrict__ resid,
           const int* __restrict__ flags) {
  __shared__ uint16_t As[128 * 32];
  __shared__ uint16_t Bs[128 * 32];
  const int tid = threadIdx.x;
  const int wid = tid >> 6, lane = tid & 63;
  const int g = lane >> 4, c = lane & 15;
  const int m0 = blockIdx.x * 128, n0 = blockIdx.y * 128;
  const int wr = wid >> 1, wc = wid & 1;
  f32x4 acc[4][4] = {};
  for (int k0 = 0; k0 < 1024; k0 += 32) {
    __syncthreads();
#pragma unroll
    for (int is = 0; is < 2; ++is) {
      int sb = is * 256 + wid * 64;
      int s = sb + lane;
      int r = s >> 2, kp = s & 3;
      int kps = kp ^ ((r >> 1) & 3);
      gload16(&As[sb * 8], A + (size_t)(m0 + r) * 1024 + k0 + kps * 8);
      gload16(&Bs[sb * 8], Bt + (size_t)(n0 + r) * 1024 + k0 + kps * 8);
    }
    __syncthreads();
    bf16x8 a[4], b[4];
#pragma unroll
    for (int mi = 0; mi < 4; ++mi) {
      int row = wr * 64 + mi * 16 + c;
      a[mi] = *(const bf16x8*)&As[row * 32 + (g ^ ((row >> 1) & 3)) * 8];
    }
#pragma unroll
    for (int ni = 0; ni < 4; ++ni) {
      int row = wc * 64 + ni * 16 + c;
      b[ni] = *(const bf16x8*)&Bs[row * 32 + (g ^ ((row >> 1) & 3)) * 8];
    }
#pragma unroll
    for (int mi = 0; mi < 4; ++mi)
#pragma unroll
      for (int ni = 0; ni < 4; ++ni)
        acc[mi][ni] = __builtin_amdgcn_mfma_f32_16x16x32_bf16(a[mi], b[ni], acc[mi][ni], 0, 0, 0);
  }
  const int f32in = flags[0];
#pragma unroll
  for (int mi = 0; mi < 4; ++mi)
#pragma unroll
    for (int ni = 0; ni < 4; ++ni)
#pragma unroll
      for (int r = 0; r < 4; ++r) {
        int mrow = m0 + wr * 64 + mi * 16 + g * 4 + r;
        int ncol = n0 + wc * 64 + ni * 16 + c;
        size_t idx = (size_t)mrow * 1024 + ncol;
        out[idx] = acc[mi][ni][r] + load_in_f(resid, idx, f32in);
      }
}

// ---------- pass 1: column stats, JBLK=64 (3 waves/SIMD, r18-proven) ----------
__global__ __launch_bounds__(256, 3)
void attn_stats(const uint16_t* __restrict__ qb, const uint16_t* __restrict__ kb,
                uint16_t* __restrict__ vt, const uint32_t* __restrict__ mbits,
                const float* __restrict__ ngbuf) {
  __shared__ float redL[4][64];
  __shared__ float invsh[64];
  const int tid = threadIdx.x, wid = tid >> 6, lane = tid & 63;
  const int g = lane >> 4, c = lane & 15;
  const int bh = blockIdx.x, b_ = bh >> 4;
  const int j0 = blockIdx.y * 64;
  const uint16_t* Kg = kb + (size_t)bh * NN * DD + (size_t)j0 * DD;
  const uint16_t* Qg = qb + (size_t)bh * NN * DD;
  const uint32_t* Mrow = mbits + (size_t)b_ * NN * 64 + (j0 >> 5);
  bf16x8 kf[2][4];
#pragma unroll
  for (int ks = 0; ks < 2; ++ks)
#pragma unroll
    for (int nj = 0; nj < 4; ++nj)
      kf[ks][nj] = *(const bf16x8*)(Kg + (size_t)(nj * 16 + c) * 64 + ks * 32 + g * 8);
  float ng4[4], l_[4];
#pragma unroll
  for (int nj = 0; nj < 4; ++nj) {
    ng4[nj] = ngbuf[b_ * NN + j0 + nj * 16 + c];
    l_[nj] = 0.f;
  }
  bf16x8 qa[2][2], qn[2][2];
  uint2 mqa[8], mqb[8];
#pragma unroll
  for (int ks = 0; ks < 2; ++ks)
#pragma unroll
    for (int mi = 0; mi < 2; ++mi)
      qa[ks][mi] = *(const bf16x8*)(Qg + (size_t)(wid * 32 + mi * 16 + c) * 64 + ks * 32 + g * 8);
#pragma unroll
  for (int u = 0; u < 8; ++u) {
    int mi = u >> 2, r = u & 3;
    mqa[u] = *(const uint2*)(Mrow + (size_t)(wid * 32 + mi * 16 + g * 4 + r) * 64);
  }

  auto body = [&](bf16x8 (&qc)[2][2], bf16x8 (&qp)[2][2],
                  uint2 (&mc)[8], uint2 (&mn)[8], int i0) {
    f32x4 sacc[2][4] = {};
    __builtin_amdgcn_s_setprio(1);
#pragma unroll
    for (int ks = 0; ks < 2; ++ks)
#pragma unroll
      for (int mi = 0; mi < 2; ++mi)
#pragma unroll
        for (int nj = 0; nj < 4; ++nj)
          sacc[mi][nj] = __builtin_amdgcn_mfma_f32_16x16x32_bf16(qc[ks][mi], kf[ks][nj], sacc[mi][nj], 0, 0, 0);
    __builtin_amdgcn_s_setprio(0);
    // prefetch next tile's Q fragments + masks (hidden under softmax)
    int ip = (i0 + 128) & (NN - 1);
#pragma unroll
    for (int ks = 0; ks < 2; ++ks)
#pragma unroll
      for (int mi = 0; mi < 2; ++mi)
        qp[ks][mi] = *(const bf16x8*)(Qg + (size_t)(ip + wid * 32 + mi * 16 + c) * 64 + ks * 32 + g * 8);
#pragma unroll
    for (int u = 0; u < 8; ++u) {
      int mi = u >> 2, r = u & 3;
      mn[u] = *(const uint2*)(Mrow + (size_t)(ip + wid * 32 + mi * 16 + g * 4 + r) * 64);
    }
#pragma unroll
    for (int mi = 0; mi < 2; ++mi)
#pragma unroll
      for (int r = 0; r < 4; ++r) {
        const uint2 mw = mc[mi * 4 + r];
#pragma unroll
        for (int nj = 0; nj < 4; ++nj) {
          uint32_t w = (nj < 2) ? mw.x : mw.y;
          bool bit = (w >> ((nj & 1) * 16 + c)) & 1u;
          float se = bit ? ng4[nj] : sacc[mi][nj][r];
          l_[nj] += EXP2(se);
        }
      }
  };
  for (int it = 0; it < 8; ++it) {
    body(qa, qn, mqa, mqb, it * 256);
    body(qn, qa, mqb, mqa, it * 256 + 128);
  }
#pragma unroll
  for (int nj = 0; nj < 4; ++nj) {
    float l = l_[nj];
    l += __shfl_xor(l, 16);
    l += __shfl_xor(l, 32);
    if (g == 0) redL[wid][nj * 16 + c] = l;
  }
  __syncthreads();
  if (tid < 64) {
    float L = redL[0][tid] + redL[1][tid] + redL[2][tid] + redL[3][tid];
    invsh[tid] = 1.0f / L;
  }
  __syncthreads();
  // scale V' = V * invL for this block's 64 columns, in place
  {
    const int d = tid >> 2, jseg = (tid & 3) * 16;
    uint16_t* vrow = vt + (size_t)bh * DD * NN + (size_t)d * NN + j0 + jseg;
#pragma unroll
    for (int u = 0; u < 2; ++u) {
      bf16x8 v = *(const bf16x8*)(vrow + u * 8);
      bf16x8 o;
#pragma unroll
      for (int e = 0; e < 8; ++e) {
        float f = bf2f((unsigned short)v[e]) * invsh[jseg + u * 8 + e];
        o[e] = (short)f2bf(f);
      }
      *(bf16x8*)(vrow + u * 8) = o;
    }
  }
}

// ---------- pass 2 (r15-proven): KVBLK=64; K,V double-buffered LDS (48KB, 3 blk/CU) ----------
__global__ __launch_bounds__(256, 3)
void attn_pv(const uint16_t* __restrict__ qb, const uint16_t* __restrict__ kb,
             const uint16_t* __restrict__ vt, const uint32_t* __restrict__ mbits,
             const float* __restrict__ ngbuf, uint16_t* __restrict__ ctxr) {
  __shared__ uint16_t Ks[2][64 * 64];
  __shared__ uint16_t Vs[2][64 * 64];
  __shared__ uint16_t Ps[128 * 64];
  const int tid = threadIdx.x, wid = tid >> 6, lane = tid & 63;
  const int g = lane >> 4, c = lane & 15;
  const int bh = blockIdx.x, b_ = bh >> 4, h = bh & 15;
  const int i0 = blockIdx.y * 128;
  const uint16_t* Qg = qb + (size_t)bh * NN * DD;
  const uint16_t* Kg = kb + (size_t)bh * NN * DD;
  const uint16_t* Vg = vt + (size_t)bh * DD * NN;
  const uint32_t* Mb = mbits + (size_t)b_ * NN * 64;
  const float* ngb = ngbuf + b_ * NN;

  auto stageK = [&](int buf, int j0) {
#pragma unroll
    for (int is = 0; is < 2; ++is) {
      int sb = is * 256 + wid * 64;
      int s = sb + lane;
      int row = s >> 3, gr = s & 7;
      gload16(&Ks[buf][sb * 8], Kg + (size_t)(j0 + row) * 64 + (gr ^ (row & 7)) * 8);
    }
  };
  auto stageV = [&](int buf, int j0) {
#pragma unroll
    for (int is = 0; is < 2; ++is) {
      int sb = is * 256 + wid * 64;
      int s = sb + lane;
      int d = s >> 3, gr = s & 7;
      gload16(&Vs[buf][sb * 8], Vg + (size_t)d * NN + j0 + (gr ^ (d & 7)) * 8);
    }
  };

  bf16x8 qf[2][2];
#pragma unroll
  for (int ks = 0; ks < 2; ++ks)
#pragma unroll
    for (int mi = 0; mi < 2; ++mi)
      qf[ks][mi] = *(const bf16x8*)(Qg + (size_t)(i0 + wid * 32 + mi * 16 + c) * 64 + ks * 32 + g * 8);

  stageK(0, 0); stageV(0, 0);
  __syncthreads();

  f32x4 cacc[2][4] = {};
  for (int t = 0; t < 32; ++t) {
    const int j0 = t * 64, cb = t & 1, nb = cb ^ 1;
    if (t < 31) { stageK(nb, j0 + 64); stageV(nb, j0 + 64); }
    // mask + negr loads issued before MFMA (latency hidden under QK^T)
    uint2 mw0 = *(const uint2*)(Mb + (size_t)(i0 + wid * 32 + c) * 64 + (j0 >> 5));
    uint2 mw1 = *(const uint2*)(Mb + (size_t)(i0 + wid * 32 + 16 + c) * 64 + (j0 >> 5));
    float4 ngv[4];
#pragma unroll
    for (int nj = 0; nj < 4; ++nj)
      ngv[nj] = *(const float4*)(ngb + j0 + nj * 16 + g * 4);
    // QK^T: S^T = mfma(K', Q)
    f32x4 st[4][2] = {};
    __builtin_amdgcn_s_setprio(1);
#pragma unroll
    for (int ks = 0; ks < 2; ++ks) {
      bf16x8 kfr[4];
#pragma unroll
      for (int nj = 0; nj < 4; ++nj) {
        int row = nj * 16 + c;
        kfr[nj] = *(const bf16x8*)&Ks[cb][row * 64 + (((ks * 4 + g) ^ (c & 7))) * 8];
      }
#pragma unroll
      for (int nj = 0; nj < 4; ++nj)
#pragma unroll
        for (int mi = 0; mi < 2; ++mi)
          st[nj][mi] = __builtin_amdgcn_mfma_f32_16x16x32_bf16(kfr[nj], qf[ks][mi], st[nj][mi], 0, 0, 0);
    }
    __builtin_amdgcn_s_setprio(0);
    // softmax: p = exp2(masked ? negr : st')   (normalizer lives in V')
    uint2 pkv[4][2];
#pragma unroll
    for (int nj = 0; nj < 4; ++nj) {
      const float4 ngq = ngv[nj];
      float nz[4] = {ngq.x, ngq.y, ngq.z, ngq.w};
#pragma unroll
      for (int mi = 0; mi < 2; ++mi) {
        const uint2 mw = mi ? mw1 : mw0;
        uint32_t w = (nj < 2) ? mw.x : mw.y;
        float p[4];
#pragma unroll
        for (int u = 0; u < 4; ++u) {
          bool bit = (w >> ((nj & 1) * 16 + g * 4 + u)) & 1u;
          float se = bit ? nz[u] : st[nj][mi][u];
          p[u] = EXP2(se);
        }
        uint32_t lo, hi;
        asm("v_cvt_pk_bf16_f32 %0, %1, %2" : "=v"(lo) : "v"(p[0]), "v"(p[1]));
        asm("v_cvt_pk_bf16_f32 %0, %1, %2" : "=v"(hi) : "v"(p[2]), "v"(p[3]));
        pkv[nj][mi] = make_uint2(lo, hi);
      }
    }
#pragma unroll
    for (int nj = 0; nj < 4; ++nj)
#pragma unroll
      for (int mi = 0; mi < 2; ++mi) {
        int iL = wid * 32 + mi * 16 + c;
        int gran = (nj * 2 + (g >> 1)) ^ (c & 7);
        *(uint2*)((char*)Ps + iL * 128 + gran * 16 + (g & 1) * 8) = pkv[nj][mi];
      }
    __syncthreads();   // B: Ps visible; stage[t+1] (issued ~1 phase ago) drained
    __builtin_amdgcn_s_setprio(1);
#pragma unroll
    for (int ks = 0; ks < 2; ++ks) {
      bf16x8 pa[2], vb[4];
#pragma unroll
      for (int mi = 0; mi < 2; ++mi) {
        int row = wid * 32 + mi * 16 + c;
        pa[mi] = *(const bf16x8*)((const char*)Ps + row * 128 + (((ks * 4 + g) ^ (c & 7))) * 16);
      }
#pragma unroll
      for (int nd = 0; nd < 4; ++nd) {
        int row = nd * 16 + c;
        vb[nd] = *(const bf16x8*)&Vs[cb][row * 64 + (((ks * 4 + g) ^ (c & 7))) * 8];
      }
#pragma unroll
      for (int mi = 0; mi < 2; ++mi)
#pragma unroll
        for (int nd = 0; nd < 4; ++nd)
          cacc[mi][nd] = __builtin_amdgcn_mfma_f32_16x16x32_bf16(pa[mi], vb[nd], cacc[mi][nd], 0, 0, 0);
    }
    __builtin_amdgcn_s_setprio(0);
    __syncthreads();   // A: PV reads done -> next tile may rewrite Ps / K,V bufs
  }
#pragma unroll
  for (int mi = 0; mi < 2; ++mi)
#pragma unroll
    for (int nd = 0; nd < 4; ++nd)
#pragma unroll
      for (int r = 0; r < 4; ++r) {
        int i = i0 + wid * 32 + mi * 16 + g * 4 + r;
        int d = nd * 16 + c;
        ctxr[((size_t)(b_ * NN + i)) * CC + h * DD + d] = f2bf(cacc[mi][nd][r]);
      }
}

// ---------- LayerNorm over C=1024 ----------
__global__ __launch_bounds__(256)
void ln_kernel(const float* __restrict__ xbuf, const void* __restrict__ gamma,
               const void* __restrict__ beta, float* __restrict__ out,
               const int* __restrict__ flags) {
  const int row = blockIdx.x;
  const int tid = threadIdx.x;
  const float4 v = ((const float4*)(xbuf + (size_t)row * CC))[tid];
  float s = v.x + v.y + v.z + v.w;
  float s2 = v.x * v.x + v.y * v.y + v.z * v.z + v.w * v.w;
#pragma unroll
  for (int off = 32; off >= 1; off >>= 1) {
    s += __shfl_xor(s, off);
    s2 += __shfl_xor(s2, off);
  }
  __shared__ float red[8];
  const int wid = tid >> 6, lane = tid & 63;
  if (lane == 0) { red[wid] = s; red[4 + wid] = s2; }
  __syncthreads();
  float ts = red[0] + red[1] + red[2] + red[3];
  float ts2 = red[4] + red[5] + red[6] + red[7];
  float mu = ts * (1.f / 1024.f);
  float var = ts2 * (1.f / 1024.f) - mu * mu;
  float rs = rsqrtf(var + 1e-5f);
  const int f32in = flags[0];
  const int cbase = tid * 4;
  float4 o;
  o.x = (v.x - mu) * rs * load_in_f(gamma, cbase + 0, f32in) + load_in_f(beta, cbase + 0, f32in);
  o.y = (v.y - mu) * rs * load_in_f(gamma, cbase + 1, f32in) + load_in_f(beta, cbase + 1, f32in);
  o.z = (v.z - mu) * rs * load_in_f(gamma, cbase + 2, f32in) + load_in_f(beta, cbase + 2, f32in);
  o.w = (v.w - mu) * rs * load_in_f(gamma, cbase + 3, f32in) + load_in_f(beta, cbase + 3, f32in);
  ((float4*)(out + (size_t)row * CC))[tid] = o;
}

// ---------- host ----------
extern "C" void kernel_launch(void* const* d_in, const int* in_sizes, int n_in,
                              void* d_out, int out_size, void* d_ws, size_t ws_size,
                              hipStream_t stream) {
  (void)in_sizes; (void)n_in; (void)out_size; (void)ws_size;
  char* ws = (char*)d_ws;
  size_t off = 0;
  auto alloc = [&](size_t bytes) -> void* {
    void* p = ws + off;
    off += (bytes + 255) & ~(size_t)255;
    return p;
  };
  int*      flags   = (int*)alloc(256);
  float*    rsbuf   = (float*)alloc((size_t)BB * NN * 4);
  float*    ngbuf   = (float*)alloc((size_t)BB * NN * 4);
  uint32_t* mbits   = (uint32_t*)alloc((size_t)BB * NN * 64 * 4);   // 2 MB bit mask
  uint16_t* xq      = (uint16_t*)alloc((size_t)BB * NN * CC * 2);
  uint16_t* xk      = (uint16_t*)alloc((size_t)BB * NN * CC * 2);
  uint16_t* xv      = (uint16_t*)alloc((size_t)BB * NN * CC * 2);
  uint16_t* qb      = (uint16_t*)alloc((size_t)BB * NN * CC * 2);
  uint16_t* kb      = (uint16_t*)alloc((size_t)BB * NN * CC * 2);
  uint16_t* vtb     = (uint16_t*)alloc((size_t)BB * NN * CC * 2);
  uint16_t* Wt      = (uint16_t*)alloc((size_t)4 * CC * CC * 2);
  uint16_t* ctxr    = xq;              // xq dead after Q projection
  float*    xbuf    = (float*)xk;      // xk+xv contiguous 32MB, dead after K/V proj

  detect_kernel<<<1, 64, 0, stream>>>((const uint32_t*)d_in[0], (const uint32_t*)d_in[4], flags);
  prep_kernel<<<dim3(2048, 1, 5), 256, 0, stream>>>(d_in[0], d_in[1], d_in[2], d_in[3], d_in[4],
                                                    xq, xk, xv, rsbuf, ngbuf, mbits, flags);
  transW<<<dim3(32, 32, 4), dim3(32, 8), 0, stream>>>(d_in[5], d_in[6], d_in[7], d_in[8], Wt, flags);

  gemmQKV<<<dim3(64, 24), 256, 0, stream>>>(xq, xk, xv, Wt, qb, kb, vtb, rsbuf);

  attn_stats<<<dim3(64, 32), 256, 0, stream>>>(qb, kb, vtb, mbits, ngbuf);
  attn_pv<<<dim3(64, 16), 256, 0, stream>>>(qb, kb, vtb, mbits, ngbuf, ctxr);

  gemmO<<<dim3(64, 8), 256, 0, stream>>>(ctxr, Wt + 3 * CC * CC, xbuf, d_in[0], flags);
  ln_kernel<<<8192, 256, 0, stream>>>(xbuf, d_in[9], d_in[10], (float*)d_out, flags);
}

// Round 21
// 396.691 us; speedup vs baseline: 1.0537x; 1.0537x over previous
//
#include <hip/hip_runtime.h>
#include <hip/hip_bf16.h>
#include <stdint.h>

#define BB 4
#define NN 2048
#define CC 1024
#define HH 16
#define DD 64

typedef __attribute__((ext_vector_type(8))) short bf16x8;
typedef __attribute__((ext_vector_type(4))) float f32x4;

#define LOG2E 1.44269504088896f

// raw v_exp_f32: D = 2^S0 (verified r12: matches exp2f numerics, absmax unchanged)
__device__ __forceinline__ float exp2_hw(float x) {
  float r;
  asm("v_exp_f32 %0, %1" : "=v"(r) : "v"(x));
  return r;
}
#define EXP2(x) exp2_hw(x)

// ---------- small helpers ----------
__device__ __forceinline__ unsigned short f2bf(float x) {
  uint32_t u = __float_as_uint(x);
  uint32_t r = (u + 0x7FFFu + ((u >> 16) & 1u)) >> 16;   // RNE
  return (unsigned short)r;
}
__device__ __forceinline__ float bf2f(unsigned short v) {
  return __uint_as_float(((uint32_t)v) << 16);
}
__device__ __forceinline__ float load_in_f(const void* p, size_t idx, int f32in) {
  if (f32in) return ((const float*)p)[idx];
  return bf2f(((const uint16_t*)p)[idx]);
}
// async global->LDS, 16B per lane; lds ptr must be the wave-uniform base
__device__ __forceinline__ void gload16(uint16_t* lds_base, const uint16_t* gsrc) {
  __builtin_amdgcn_global_load_lds(
      (const __attribute__((address_space(1))) uint32_t*)(const void*)gsrc,
      (__attribute__((address_space(3))) uint32_t*)(void*)lds_base,
      16, 0, 0);
}

// ---------- dtype detection ----------
__global__ void detect_kernel(const uint32_t* __restrict__ q,
                              const uint32_t* __restrict__ m,
                              int* __restrict__ flags) {
  if (threadIdx.x == 0 && blockIdx.x == 0) {
    int sane = 0;
    for (int i = 0; i < 128; ++i) {
      uint32_t w = q[i];
      int e0 = (int)((w >> 7) & 0xFFu);
      int e1 = (int)((w >> 23) & 0xFFu);
      sane += (e0 >= 0x70 && e0 <= 0x8F) ? 1 : 0;
      sane += (e1 >= 0x70 && e1 <= 0x8F) ? 1 : 0;
    }
    flags[0] = (sane >= 208) ? 0 : 1;   // 1 => fp32 inputs
    int allsmall = 1;
    for (int i = 0; i < 16; ++i) if (m[i] > 1u) allsmall = 0;
    flags[1] = allsmall;                 // 1 => mask is int32
  }
}

// ---------- merged prep: z=0..2 qkv->bf16, z=3 mask bitpack, z=4 ratio ----------
__global__ void prep_kernel(const void* __restrict__ s0, const void* __restrict__ s1,
                            const void* __restrict__ s2, const void* __restrict__ ratio,
                            const void* __restrict__ mask,
                            uint16_t* __restrict__ d0, uint16_t* __restrict__ d1,
                            uint16_t* __restrict__ d2,
                            float* __restrict__ rs, float* __restrict__ ng,
                            uint32_t* __restrict__ mb, const int* __restrict__ flags) {
  const int z = blockIdx.z;
  if (z < 3) {
    const int f32in = flags[0];
    const void* src = (z == 0) ? s0 : (z == 1) ? s1 : s2;
    uint16_t* dst = (z == 0) ? d0 : (z == 1) ? d1 : d2;
    int idx = blockIdx.x * blockDim.x + threadIdx.x;
    const int total = (BB * NN * CC) >> 2;
    const int stride = gridDim.x * blockDim.x;
    if (f32in) {
      const float4* s = (const float4*)src;
      for (; idx < total; idx += stride) {
        float4 v = s[idx];
        ushort4 o;
        o.x = f2bf(v.x); o.y = f2bf(v.y); o.z = f2bf(v.z); o.w = f2bf(v.w);
        ((ushort4*)dst)[idx] = o;
      }
    } else {
      const ushort4* s = (const ushort4*)src;
      for (; idx < total; idx += stride) ((ushort4*)dst)[idx] = s[idx];
    }
  } else if (z == 3) {
    const int isint = flags[1];
    const int gw = (blockIdx.x * blockDim.x + threadIdx.x) >> 6;
    const int lane = threadIdx.x & 63;
    const int nw = (gridDim.x * blockDim.x) >> 6;
    const int totalw = (BB * NN * NN) >> 6;
    for (int w = gw; w < totalw; w += nw) {
      int e = w * 64 + lane;
      bool m;
      if (isint) m = (((const int*)mask)[e] != 0);
      else       m = (((const uint8_t*)mask)[e] != 0);
      unsigned long long bal = __ballot(m);
      if (lane == 0) ((unsigned long long*)mb)[w] = bal;
    }
  } else {
    const int f32in = flags[0];
    int idx = blockIdx.x * blockDim.x + threadIdx.x;
    if (idx < BB * NN) {
      float r = load_in_f(ratio, idx, f32in);
      rs[idx] = r * 0.125f * LOG2E;
      ng[idx] = r * (-1e9f) * LOG2E;
    }
  }
}

// ---------- W transpose + bf16 convert: Wt[n][k] = W[k][n] ----------
__global__ __launch_bounds__(256)
void transW(const void* w0, const void* w1, const void* w2, const void* w3,
            uint16_t* __restrict__ wt, const int* __restrict__ flags) {
  const int f32in = flags[0];
  const void* src = (blockIdx.z == 0) ? w0 : (blockIdx.z == 1) ? w1
                   : (blockIdx.z == 2) ? w2 : w3;
  uint16_t* dst = wt + (size_t)blockIdx.z * CC * CC;
  __shared__ float t[32][33];
  const int tx = threadIdx.x, ty = threadIdx.y;
  const int n0 = blockIdx.x * 32, k0 = blockIdx.y * 32;
#pragma unroll
  for (int r = 0; r < 4; ++r) {
    int k = k0 + ty + r * 8;
    t[ty + r * 8][tx] = load_in_f(src, (size_t)k * CC + n0 + tx, f32in);
  }
  __syncthreads();
#pragma unroll
  for (int r = 0; r < 4; ++r) {
    int n = n0 + ty + r * 8;
    dst[(size_t)n * CC + k0 + tx] = f2bf(t[tx][ty + r * 8]);
  }
}

// ---------- fused QKV projection: grid (64, 24); blockIdx.y selects q/k/v third ----------
__global__ __launch_bounds__(256, 2)
void gemmQKV(const uint16_t* __restrict__ xq, const uint16_t* __restrict__ xk,
             const uint16_t* __restrict__ xv, const uint16_t* __restrict__ Wt,
             uint16_t* __restrict__ qb, uint16_t* __restrict__ kb,
             uint16_t* __restrict__ vtb, const float* __restrict__ rowscale) {
  __shared__ uint16_t As[128 * 32];
  __shared__ uint16_t Bs[128 * 32];
  const int tid = threadIdx.x;
  const int wid = tid >> 6, lane = tid & 63;
  const int g = lane >> 4, c = lane & 15;
  const int n0g = blockIdx.y * 128;
  const int sel = n0g >> 10;
  const int n0 = n0g & 1023;
  const int m0 = blockIdx.x * 128;
  const uint16_t* A = (sel == 0) ? xq : (sel == 1) ? xk : xv;
  const uint16_t* Bt = Wt + (size_t)sel * CC * CC;
  const int wr = wid >> 1, wc = wid & 1;
  f32x4 acc[4][4] = {};
  for (int k0 = 0; k0 < 1024; k0 += 32) {
    __syncthreads();
#pragma unroll
    for (int is = 0; is < 2; ++is) {
      int sb = is * 256 + wid * 64;
      int s = sb + lane;
      int r = s >> 2, kp = s & 3;
      int kps = kp ^ ((r >> 1) & 3);
      gload16(&As[sb * 8], A + (size_t)(m0 + r) * 1024 + k0 + kps * 8);
      gload16(&Bs[sb * 8], Bt + (size_t)(n0 + r) * 1024 + k0 + kps * 8);
    }
    __syncthreads();
    bf16x8 a[4], b[4];
#pragma unroll
    for (int mi = 0; mi < 4; ++mi) {
      int row = wr * 64 + mi * 16 + c;
      a[mi] = *(const bf16x8*)&As[row * 32 + (g ^ ((row >> 1) & 3)) * 8];
    }
#pragma unroll
    for (int ni = 0; ni < 4; ++ni) {
      int row = wc * 64 + ni * 16 + c;
      b[ni] = *(const bf16x8*)&Bs[row * 32 + (g ^ ((row >> 1) & 3)) * 8];
    }
#pragma unroll
    for (int mi = 0; mi < 4; ++mi)
#pragma unroll
      for (int ni = 0; ni < 4; ++ni)
        acc[mi][ni] = __builtin_amdgcn_mfma_f32_16x16x32_bf16(a[mi], b[ni], acc[mi][ni], 0, 0, 0);
  }
  float rsv[4][4];
  if (sel == 1) {
#pragma unroll
    for (int mi = 0; mi < 4; ++mi)
#pragma unroll
      for (int r = 0; r < 4; ++r)
        rsv[mi][r] = rowscale[m0 + wr * 64 + mi * 16 + g * 4 + r];
  }
#pragma unroll
  for (int mi = 0; mi < 4; ++mi)
#pragma unroll
    for (int ni = 0; ni < 4; ++ni)
#pragma unroll
      for (int r = 0; r < 4; ++r) {
        int mrow = m0 + wr * 64 + mi * 16 + g * 4 + r;
        int ncol = n0 + wc * 64 + ni * 16 + c;
        float v = acc[mi][ni][r];
        int b_ = mrow >> 11, i = mrow & 2047, h = ncol >> 6, d = ncol & 63;
        if (sel == 0) {
          qb[((size_t)(b_ * 16 + h) * 2048 + i) * 64 + d] = f2bf(v);
        } else if (sel == 1) {
          kb[((size_t)(b_ * 16 + h) * 2048 + i) * 64 + d] = f2bf(v * rsv[mi][r]);
        } else {
          vtb[((size_t)(b_ * 16 + h) * 64 + d) * 2048 + i] = f2bf(v);
        }
      }
}

// ---------- output GEMM: out fp32 [M][C] = acc + resid ----------
__global__ __launch_bounds__(256, 2)
void gemmO(const uint16_t* __restrict__ A, const uint16_t* __restrict__ Bt,
           float* __restrict__ out, const void* __restrict__ resid,
           const int* __restrict__ flags) {
  __shared__ uint16_t As[128 * 32];
  __shared__ uint16_t Bs[128 * 32];
  const int tid = threadIdx.x;
  const int wid = tid >> 6, lane = tid & 63;
  const int g = lane >> 4, c = lane & 15;
  const int m0 = blockIdx.x * 128, n0 = blockIdx.y * 128;
  const int wr = wid >> 1, wc = wid & 1;
  f32x4 acc[4][4] = {};
  for (int k0 = 0; k0 < 1024; k0 += 32) {
    __syncthreads();
#pragma unroll
    for (int is = 0; is < 2; ++is) {
      int sb = is * 256 + wid * 64;
      int s = sb + lane;
      int r = s >> 2, kp = s & 3;
      int kps = kp ^ ((r >> 1) & 3);
      gload16(&As[sb * 8], A + (size_t)(m0 + r) * 1024 + k0 + kps * 8);
      gload16(&Bs[sb * 8], Bt + (size_t)(n0 + r) * 1024 + k0 + kps * 8);
    }
    __syncthreads();
    bf16x8 a[4], b[4];
#pragma unroll
    for (int mi = 0; mi < 4; ++mi) {
      int row = wr * 64 + mi * 16 + c;
      a[mi] = *(const bf16x8*)&As[row * 32 + (g ^ ((row >> 1) & 3)) * 8];
    }
#pragma unroll
    for (int ni = 0; ni < 4; ++ni) {
      int row = wc * 64 + ni * 16 + c;
      b[ni] = *(const bf16x8*)&Bs[row * 32 + (g ^ ((row >> 1) & 3)) * 8];
    }
#pragma unroll
    for (int mi = 0; mi < 4; ++mi)
#pragma unroll
      for (int ni = 0; ni < 4; ++ni)
        acc[mi][ni] = __builtin_amdgcn_mfma_f32_16x16x32_bf16(a[mi], b[ni], acc[mi][ni], 0, 0, 0);
  }
  const int f32in = flags[0];
#pragma unroll
  for (int mi = 0; mi < 4; ++mi)
#pragma unroll
    for (int ni = 0; ni < 4; ++ni)
#pragma unroll
      for (int r = 0; r < 4; ++r) {
        int mrow = m0 + wr * 64 + mi * 16 + g * 4 + r;
        int ncol = n0 + wc * 64 + ni * 16 + c;
        size_t idx = (size_t)mrow * 1024 + ncol;
        out[idx] = acc[mi][ni][r] + load_in_f(resid, idx, f32in);
      }
}

// ---------- pass 1: column stats, JBLK=64 (3 waves/SIMD, r18-proven) ----------
__global__ __launch_bounds__(256, 3)
void attn_stats(const uint16_t* __restrict__ qb, const uint16_t* __restrict__ kb,
                uint16_t* __restrict__ vt, const uint32_t* __restrict__ mbits,
                const float* __restrict__ ngbuf) {
  __shared__ float redL[4][64];
  __shared__ float invsh[64];
  const int tid = threadIdx.x, wid = tid >> 6, lane = tid & 63;
  const int g = lane >> 4, c = lane & 15;
  const int bh = blockIdx.x, b_ = bh >> 4;
  const int j0 = blockIdx.y * 64;
  const uint16_t* Kg = kb + (size_t)bh * NN * DD + (size_t)j0 * DD;
  const uint16_t* Qg = qb + (size_t)bh * NN * DD;
  const uint32_t* Mrow = mbits + (size_t)b_ * NN * 64 + (j0 >> 5);
  bf16x8 kf[2][4];
#pragma unroll
  for (int ks = 0; ks < 2; ++ks)
#pragma unroll
    for (int nj = 0; nj < 4; ++nj)
      kf[ks][nj] = *(const bf16x8*)(Kg + (size_t)(nj * 16 + c) * 64 + ks * 32 + g * 8);
  float ng4[4], l_[4];
#pragma unroll
  for (int nj = 0; nj < 4; ++nj) {
    ng4[nj] = ngbuf[b_ * NN + j0 + nj * 16 + c];
    l_[nj] = 0.f;
  }
  bf16x8 qa[2][2], qn[2][2];
  uint2 mqa[8], mqb[8];
#pragma unroll
  for (int ks = 0; ks < 2; ++ks)
#pragma unroll
    for (int mi = 0; mi < 2; ++mi)
      qa[ks][mi] = *(const bf16x8*)(Qg + (size_t)(wid * 32 + mi * 16 + c) * 64 + ks * 32 + g * 8);
#pragma unroll
  for (int u = 0; u < 8; ++u) {
    int mi = u >> 2, r = u & 3;
    mqa[u] = *(const uint2*)(Mrow + (size_t)(wid * 32 + mi * 16 + g * 4 + r) * 64);
  }

  auto body = [&](bf16x8 (&qc)[2][2], bf16x8 (&qp)[2][2],
                  uint2 (&mc)[8], uint2 (&mn)[8], int i0) {
    f32x4 sacc[2][4] = {};
    __builtin_amdgcn_s_setprio(1);
#pragma unroll
    for (int ks = 0; ks < 2; ++ks)
#pragma unroll
      for (int mi = 0; mi < 2; ++mi)
#pragma unroll
        for (int nj = 0; nj < 4; ++nj)
          sacc[mi][nj] = __builtin_amdgcn_mfma_f32_16x16x32_bf16(qc[ks][mi], kf[ks][nj], sacc[mi][nj], 0, 0, 0);
    __builtin_amdgcn_s_setprio(0);
    // prefetch next tile's Q fragments + masks (hidden under softmax)
    int ip = (i0 + 128) & (NN - 1);
#pragma unroll
    for (int ks = 0; ks < 2; ++ks)
#pragma unroll
      for (int mi = 0; mi < 2; ++mi)
        qp[ks][mi] = *(const bf16x8*)(Qg + (size_t)(ip + wid * 32 + mi * 16 + c) * 64 + ks * 32 + g * 8);
#pragma unroll
    for (int u = 0; u < 8; ++u) {
      int mi = u >> 2, r = u & 3;
      mn[u] = *(const uint2*)(Mrow + (size_t)(ip + wid * 32 + mi * 16 + g * 4 + r) * 64);
    }
#pragma unroll
    for (int mi = 0; mi < 2; ++mi)
#pragma unroll
      for (int r = 0; r < 4; ++r) {
        const uint2 mw = mc[mi * 4 + r];
#pragma unroll
        for (int nj = 0; nj < 4; ++nj) {
          uint32_t w = (nj < 2) ? mw.x : mw.y;
          bool bit = (w >> ((nj & 1) * 16 + c)) & 1u;
          float se = bit ? ng4[nj] : sacc[mi][nj][r];
          l_[nj] += EXP2(se);
        }
      }
  };
  for (int it = 0; it < 8; ++it) {
    body(qa, qn, mqa, mqb, it * 256);
    body(qn, qa, mqb, mqa, it * 256 + 128);
  }
#pragma unroll
  for (int nj = 0; nj < 4; ++nj) {
    float l = l_[nj];
    l += __shfl_xor(l, 16);
    l += __shfl_xor(l, 32);
    if (g == 0) redL[wid][nj * 16 + c] = l;
  }
  __syncthreads();
  if (tid < 64) {
    float L = redL[0][tid] + redL[1][tid] + redL[2][tid] + redL[3][tid];
    invsh[tid] = 1.0f / L;
  }
  __syncthreads();
  // scale V' = V * invL for this block's 64 columns, in place
  {
    const int d = tid >> 2, jseg = (tid & 3) * 16;
    uint16_t* vrow = vt + (size_t)bh * DD * NN + (size_t)d * NN + j0 + jseg;
#pragma unroll
    for (int u = 0; u < 2; ++u) {
      bf16x8 v = *(const bf16x8*)(vrow + u * 8);
      bf16x8 o;
#pragma unroll
      for (int e = 0; e < 8; ++e) {
        float f = bf2f((unsigned short)v[e]) * invsh[jseg + u * 8 + e];
        o[e] = (short)f2bf(f);
      }
      *(bf16x8*)(vrow + u * 8) = o;
    }
  }
}

// ---------- pass 2: IBLK=256, KVBLK=64; K,V dbuf + Ps[256][64] (64KB, 2 blk/CU);
// 2x MFMA per barrier pair vs r18 (amortizes stage/drain overhead) ----------
__global__ __launch_bounds__(256, 2)
void attn_pv(const uint16_t* __restrict__ qb, const uint16_t* __restrict__ kb,
             const uint16_t* __restrict__ vt, const uint32_t* __restrict__ mbits,
             const float* __restrict__ ngbuf, uint16_t* __restrict__ ctxr) {
  __shared__ uint16_t Ks[2][64 * 64];
  __shared__ uint16_t Vs[2][64 * 64];
  __shared__ uint16_t Ps[256 * 64];
  const int tid = threadIdx.x, wid = tid >> 6, lane = tid & 63;
  const int g = lane >> 4, c = lane & 15;
  const int bh = blockIdx.x, b_ = bh >> 4, h = bh & 15;
  const int i0 = blockIdx.y * 256;
  const uint16_t* Qg = qb + (size_t)bh * NN * DD;
  const uint16_t* Kg = kb + (size_t)bh * NN * DD;
  const uint16_t* Vg = vt + (size_t)bh * DD * NN;
  const uint32_t* Mb = mbits + (size_t)b_ * NN * 64;
  const float* ngb = ngbuf + b_ * NN;

  auto stageK = [&](int buf, int j0) {
#pragma unroll
    for (int is = 0; is < 2; ++is) {
      int sb = is * 256 + wid * 64;
      int s = sb + lane;
      int row = s >> 3, gr = s & 7;
      gload16(&Ks[buf][sb * 8], Kg + (size_t)(j0 + row) * 64 + (gr ^ (row & 7)) * 8);
    }
  };
  auto stageV = [&](int buf, int j0) {
#pragma unroll
    for (int is = 0; is < 2; ++is) {
      int sb = is * 256 + wid * 64;
      int s = sb + lane;
      int d = s >> 3, gr = s & 7;
      gload16(&Vs[buf][sb * 8], Vg + (size_t)d * NN + j0 + (gr ^ (d & 7)) * 8);
    }
  };

  // Q fragments: each wave owns 64 i-rows (4 sub-tiles of 16)
  bf16x8 qf[2][4];
#pragma unroll
  for (int ks = 0; ks < 2; ++ks)
#pragma unroll
    for (int mi = 0; mi < 4; ++mi)
      qf[ks][mi] = *(const bf16x8*)(Qg + (size_t)(i0 + wid * 64 + mi * 16 + c) * 64 + ks * 32 + g * 8);

  stageK(0, 0); stageV(0, 0);
  __syncthreads();

  f32x4 cacc[4][4] = {};
  for (int t = 0; t < 32; ++t) {
    const int j0 = t * 64, cb = t & 1, nb = cb ^ 1;
    if (t < 31) { stageK(nb, j0 + 64); stageV(nb, j0 + 64); }
    // mask + negr loads issued before MFMA (latency hidden under QK^T)
    uint2 mwm[4];
#pragma unroll
    for (int mi = 0; mi < 4; ++mi)
      mwm[mi] = *(const uint2*)(Mb + (size_t)(i0 + wid * 64 + mi * 16 + c) * 64 + (j0 >> 5));
    float4 ngv[4];
#pragma unroll
    for (int nj = 0; nj < 4; ++nj)
      ngv[nj] = *(const float4*)(ngb + j0 + nj * 16 + g * 4);
    // QK^T: S^T = mfma(K', Q)  -- 32 MFMA
    f32x4 st[4][4] = {};
    __builtin_amdgcn_s_setprio(1);
#pragma unroll
    for (int ks = 0; ks < 2; ++ks) {
      bf16x8 kfr[4];
#pragma unroll
      for (int nj = 0; nj < 4; ++nj) {
        int row = nj * 16 + c;
        kfr[nj] = *(const bf16x8*)&Ks[cb][row * 64 + (((ks * 4 + g) ^ (c & 7))) * 8];
      }
#pragma unroll
      for (int nj = 0; nj < 4; ++nj)
#pragma unroll
        for (int mi = 0; mi < 4; ++mi)
          st[nj][mi] = __builtin_amdgcn_mfma_f32_16x16x32_bf16(kfr[nj], qf[ks][mi], st[nj][mi], 0, 0, 0);
    }
    __builtin_amdgcn_s_setprio(0);
    // softmax: p = exp2(masked ? negr : st')   (normalizer lives in V')
#pragma unroll
    for (int nj = 0; nj < 4; ++nj) {
      const float4 ngq = ngv[nj];
      float nz[4] = {ngq.x, ngq.y, ngq.z, ngq.w};
#pragma unroll
      for (int mi = 0; mi < 4; ++mi) {
        const uint2 mw = mwm[mi];
        uint32_t w = (nj < 2) ? mw.x : mw.y;
        float p[4];
#pragma unroll
        for (int u = 0; u < 4; ++u) {
          bool bit = (w >> ((nj & 1) * 16 + g * 4 + u)) & 1u;
          float se = bit ? nz[u] : st[nj][mi][u];
          p[u] = EXP2(se);
        }
        uint32_t lo, hi;
        asm("v_cvt_pk_bf16_f32 %0, %1, %2" : "=v"(lo) : "v"(p[0]), "v"(p[1]));
        asm("v_cvt_pk_bf16_f32 %0, %1, %2" : "=v"(hi) : "v"(p[2]), "v"(p[3]));
        int iL = wid * 64 + mi * 16 + c;
        int gran = (nj * 2 + (g >> 1)) ^ (c & 7);
        *(uint2*)((char*)Ps + iL * 128 + gran * 16 + (g & 1) * 8) = make_uint2(lo, hi);
      }
    }
    __syncthreads();   // B: Ps visible; stage[t+1] (issued ~1 tile of compute ago) drained
    __builtin_amdgcn_s_setprio(1);
#pragma unroll
    for (int ks = 0; ks < 2; ++ks) {
      bf16x8 pa[4], vb[4];
#pragma unroll
      for (int mi = 0; mi < 4; ++mi) {
        int row = wid * 64 + mi * 16 + c;
        pa[mi] = *(const bf16x8*)((const char*)Ps + row * 128 + (((ks * 4 + g) ^ (c & 7))) * 16);
      }
#pragma unroll
      for (int nd = 0; nd < 4; ++nd) {
        int row = nd * 16 + c;
        vb[nd] = *(const bf16x8*)&Vs[cb][row * 64 + (((ks * 4 + g) ^ (c & 7))) * 8];
      }
#pragma unroll
      for (int mi = 0; mi < 4; ++mi)
#pragma unroll
        for (int nd = 0; nd < 4; ++nd)
          cacc[mi][nd] = __builtin_amdgcn_mfma_f32_16x16x32_bf16(pa[mi], vb[nd], cacc[mi][nd], 0, 0, 0);
    }
    __builtin_amdgcn_s_setprio(0);
    __syncthreads();   // A: PV reads done -> next tile may rewrite Ps / K,V bufs
  }
#pragma unroll
  for (int mi = 0; mi < 4; ++mi)
#pragma unroll
    for (int nd = 0; nd < 4; ++nd)
#pragma unroll
      for (int r = 0; r < 4; ++r) {
        int i = i0 + wid * 64 + mi * 16 + g * 4 + r;
        int d = nd * 16 + c;
        ctxr[((size_t)(b_ * NN + i)) * CC + h * DD + d] = f2bf(cacc[mi][nd][r]);
      }
}

// ---------- LayerNorm over C=1024 ----------
__global__ __launch_bounds__(256)
void ln_kernel(const float* __restrict__ xbuf, const void* __restrict__ gamma,
               const void* __restrict__ beta, float* __restrict__ out,
               const int* __restrict__ flags) {
  const int row = blockIdx.x;
  const int tid = threadIdx.x;
  const float4 v = ((const float4*)(xbuf + (size_t)row * CC))[tid];
  float s = v.x + v.y + v.z + v.w;
  float s2 = v.x * v.x + v.y * v.y + v.z * v.z + v.w * v.w;
#pragma unroll
  for (int off = 32; off >= 1; off >>= 1) {
    s += __shfl_xor(s, off);
    s2 += __shfl_xor(s2, off);
  }
  __shared__ float red[8];
  const int wid = tid >> 6, lane = tid & 63;
  if (lane == 0) { red[wid] = s; red[4 + wid] = s2; }
  __syncthreads();
  float ts = red[0] + red[1] + red[2] + red[3];
  float ts2 = red[4] + red[5] + red[6] + red[7];
  float mu = ts * (1.f / 1024.f);
  float var = ts2 * (1.f / 1024.f) - mu * mu;
  float rs = rsqrtf(var + 1e-5f);
  const int f32in = flags[0];
  const int cbase = tid * 4;
  float4 o;
  o.x = (v.x - mu) * rs * load_in_f(gamma, cbase + 0, f32in) + load_in_f(beta, cbase + 0, f32in);
  o.y = (v.y - mu) * rs * load_in_f(gamma, cbase + 1, f32in) + load_in_f(beta, cbase + 1, f32in);
  o.z = (v.z - mu) * rs * load_in_f(gamma, cbase + 2, f32in) + load_in_f(beta, cbase + 2, f32in);
  o.w = (v.w - mu) * rs * load_in_f(gamma, cbase + 3, f32in) + load_in_f(beta, cbase + 3, f32in);
  ((float4*)(out + (size_t)row * CC))[tid] = o;
}

// ---------- host ----------
extern "C" void kernel_launch(void* const* d_in, const int* in_sizes, int n_in,
                              void* d_out, int out_size, void* d_ws, size_t ws_size,
                              hipStream_t stream) {
  (void)in_sizes; (void)n_in; (void)out_size; (void)ws_size;
  char* ws = (char*)d_ws;
  size_t off = 0;
  auto alloc = [&](size_t bytes) -> void* {
    void* p = ws + off;
    off += (bytes + 255) & ~(size_t)255;
    return p;
  };
  int*      flags   = (int*)alloc(256);
  float*    rsbuf   = (float*)alloc((size_t)BB * NN * 4);
  float*    ngbuf   = (float*)alloc((size_t)BB * NN * 4);
  uint32_t* mbits   = (uint32_t*)alloc((size_t)BB * NN * 64 * 4);   // 2 MB bit mask
  uint16_t* xq      = (uint16_t*)alloc((size_t)BB * NN * CC * 2);
  uint16_t* xk      = (uint16_t*)alloc((size_t)BB * NN * CC * 2);
  uint16_t* xv      = (uint16_t*)alloc((size_t)BB * NN * CC * 2);
  uint16_t* qb      = (uint16_t*)alloc((size_t)BB * NN * CC * 2);
  uint16_t* kb      = (uint16_t*)alloc((size_t)BB * NN * CC * 2);
  uint16_t* vtb     = (uint16_t*)alloc((size_t)BB * NN * CC * 2);
  uint16_t* Wt      = (uint16_t*)alloc((size_t)4 * CC * CC * 2);
  uint16_t* ctxr    = xq;              // xq dead after Q projection
  float*    xbuf    = (float*)xk;      // xk+xv contiguous 32MB, dead after K/V proj

  detect_kernel<<<1, 64, 0, stream>>>((const uint32_t*)d_in[0], (const uint32_t*)d_in[4], flags);
  prep_kernel<<<dim3(2048, 1, 5), 256, 0, stream>>>(d_in[0], d_in[1], d_in[2], d_in[3], d_in[4],
                                                    xq, xk, xv, rsbuf, ngbuf, mbits, flags);
  transW<<<dim3(32, 32, 4), dim3(32, 8), 0, stream>>>(d_in[5], d_in[6], d_in[7], d_in[8], Wt, flags);

  gemmQKV<<<dim3(64, 24), 256, 0, stream>>>(xq, xk, xv, Wt, qb, kb, vtb, rsbuf);

  attn_stats<<<dim3(64, 32), 256, 0, stream>>>(qb, kb, vtb, mbits, ngbuf);
  attn_pv<<<dim3(64, 8), 256, 0, stream>>>(qb, kb, vtb, mbits, ngbuf, ctxr);

  gemmO<<<dim3(64, 8), 256, 0, stream>>>(ctxr, Wt + 3 * CC * CC, xbuf, d_in[0], flags);
  ln_kernel<<<8192, 256, 0, stream>>>(xbuf, d_in[9], d_in[10], (float*)d_out, flags);
}